// Round 1
// baseline (2238.033 us; speedup 1.0000x reference)
//
#include <hip/hip_runtime.h>
#include <hip/hip_bf16.h>
#include <math.h>

#define HD 128
#define KN 8
#define EM 10
#define MPB 2     // motifs per block (kernel1)
#define EPB 2     // motif-edges per block (kernel2)

// ws float layout (precomputed tables)
#define WS_TE   0        // 16*128  : (type_emb[s]+type_emb[e]) @ me_W[0:128]
#define WS_TM   2048     // 4*128   : tnode(type) @ motif_W[128:256]
#define WS_AW2  2560     // 9*128   : atom_W @ me_W[128:256]
#define WS_EW2  3712     // 3*128   : edge_W @ me_W[128:256]
#define WS_CVEC 4096     // 128     : me_b + (6*atom_b+8*edge_b) @ me_W[128:256]

__global__ __launch_bounds__(128) void precompute_kernel(
    const float* __restrict__ type_emb, const float* __restrict__ atom_W,
    const float* __restrict__ atom_b, const float* __restrict__ edge_W,
    const float* __restrict__ edge_b, const float* __restrict__ motif_W,
    const float* __restrict__ me_W, const float* __restrict__ me_b,
    float n_nodes, float* __restrict__ ws)
{
  const int t = threadIdx.x;   // 0..127
  const int r = blockIdx.x;    // 0..32
  float acc = 0.0f;
  if (r < 16) {                         // TE: 16 type combos through me_W top half
    const int sc = r >> 2, ec = r & 3;
    for (int c = 0; c < HD; ++c)
      acc += (type_emb[sc*HD + c] + type_emb[ec*HD + c]) * me_W[c*HD + t];
    ws[WS_TE + r*HD + t] = acc;
  } else if (r < 20) {                  // TM: tnode(type) through motif_W bottom half
    const int ty = r - 16;
    for (int c = 0; c < HD; ++c) {
      float tv = type_emb[ty*HD + c] * (c >= 64 ? n_nodes : 1.0f);
      acc += tv * motif_W[(HD + c)*HD + t];
    }
    ws[WS_TM + ty*HD + t] = acc;
  } else if (r < 29) {                  // AW2 = atom_W @ me_W bottom half
    const int a = r - 20;
    for (int c = 0; c < HD; ++c)
      acc += atom_W[a*HD + c] * me_W[(HD + c)*HD + t];
    ws[WS_AW2 + a*HD + t] = acc;
  } else if (r < 32) {                  // EW2 = edge_W @ me_W bottom half
    const int a = r - 29;
    for (int c = 0; c < HD; ++c)
      acc += edge_W[a*HD + c] * me_W[(HD + c)*HD + t];
    ws[WS_EW2 + a*HD + t] = acc;
  } else {                              // cvec
    acc = me_b[t];
    for (int c = 0; c < HD; ++c)
      acc += (6.0f*atom_b[c] + 8.0f*edge_b[c]) * me_W[(HD + c)*HD + t];
    ws[WS_CVEC + t] = acc;
  }
}

__global__ __launch_bounds__(256, 4) void motif_kernel(
    const float* __restrict__ x, const float* __restrict__ eag,
    const int* __restrict__ motif_nodes, const int* __restrict__ motif_types,
    const int* __restrict__ m_src, const int* __restrict__ m_dst,
    const int* __restrict__ m_eidx,
    const float* __restrict__ atom_W, const float* __restrict__ atom_b,
    const float* __restrict__ edge_W, const float* __restrict__ edge_b,
    const float* __restrict__ conv_W1, const float* __restrict__ conv_b1,
    const float* __restrict__ conv_W2, const float* __restrict__ conv_b2,
    const float* __restrict__ conv_eps,
    const float* __restrict__ attn_W, const float* __restrict__ attn_b,
    const float* __restrict__ emlp_W, const float* __restrict__ emlp_b,
    const float* __restrict__ motif_W, const float* __restrict__ motif_b,
    const float* __restrict__ ws, float* __restrict__ out)
{
  __shared__ float bufA[MPB*KN*HD];      // 8 KB
  __shared__ float bufB[MPB*KN*HD];      // 8 KB
  __shared__ float EA[MPB*EM*HD];        // 10 KB
  __shared__ float catb[MPB][HD];
  __shared__ float als[MPB][KN];
  __shared__ int   nidx[MPB][KN];
  __shared__ int   sidx[MPB][EM];
  __shared__ int   didx[MPB][EM];
  __shared__ int   geidx[MPB][EM];
  __shared__ float xr[MPB*KN][9];
  __shared__ float er[MPB*EM][3];
  __shared__ int   tty[MPB];

  const int tid = threadIdx.x;
  const int t   = tid & (HD - 1);   // channel
  const int g   = tid >> 7;         // motif within block
  const int m0  = blockIdx.x * MPB;

  // ---- load indices
  if (tid < MPB*KN) { int gm = tid/KN, k = tid%KN; nidx[gm][k] = motif_nodes[(m0+gm)*KN + k]; }
  if (tid >= 64 && tid < 64 + MPB*EM)  { int i = tid-64;  sidx[i/EM][i%EM]  = m_src [(m0+i/EM)*EM + i%EM]; }
  if (tid >= 96 && tid < 96 + MPB*EM)  { int i = tid-96;  didx[i/EM][i%EM]  = m_dst [(m0+i/EM)*EM + i%EM]; }
  if (tid >= 128 && tid < 128 + MPB*EM){ int i = tid-128; geidx[i/EM][i%EM] = m_eidx[(m0+i/EM)*EM + i%EM]; }
  if (tid >= 160 && tid < 160 + MPB)   { tty[tid-160] = motif_types[m0 + tid - 160]; }
  __syncthreads();

  // ---- gather raw features
  for (int i = tid; i < MPB*KN*9; i += 256) { int row = i/9, a = i%9; xr[row][a] = x[nidx[row/KN][row%KN]*9 + a]; }
  for (int i = tid; i < MPB*EM*3; i += 256) { int row = i/3, a = i%3; er[row][a] = eag[geidx[row/EM][row%EM]*3 + a]; }
  __syncthreads();

  float* cur = bufA;
  float* tmp = bufB;

  // ---- h = x[nodes] @ atom_W + atom_b
  {
    float aw[9];
    #pragma unroll
    for (int a = 0; a < 9; ++a) aw[a] = atom_W[a*HD + t];
    const float ab = atom_b[t];
    #pragma unroll
    for (int k = 0; k < KN; ++k) {
      float acc = ab;
      #pragma unroll
      for (int a = 0; a < 9; ++a) acc += xr[g*KN + k][a] * aw[a];
      cur[(g*KN + k)*HD + t] = acc;
    }
  }
  // ---- ea = edge_attr[eidx] @ edge_W + edge_b
  {
    const float ew0 = edge_W[t], ew1 = edge_W[HD + t], ew2 = edge_W[2*HD + t];
    const float eb = edge_b[t];
    #pragma unroll
    for (int e = 0; e < EM; ++e) {
      const int row = g*EM + e;
      EA[row*HD + t] = eb + er[row][0]*ew0 + er[row][1]*ew1 + er[row][2]*ew2;
    }
  }
  __syncthreads();

  // ---- conv layers
  #pragma unroll
  for (int l = 0; l < 2; ++l) {
    const float epl = 1.0f + conv_eps[l];
    const float* W1 = conv_W1 + l*HD*HD;
    const float* W2 = conv_W2 + l*HD*HD;
    const float b1 = conv_b1[l*HD + t];
    const float b2 = conv_b2[l*HD + t];

    // z = (1+eps)*h + scatter_dst(ea * h[src])
    #pragma unroll
    for (int k = 0; k < KN; ++k) tmp[(g*KN + k)*HD + t] = epl * cur[(g*KN + k)*HD + t];
    #pragma unroll
    for (int e = 0; e < EM; ++e) {
      const int s = sidx[g][e], d = didx[g][e];
      tmp[(g*KN + d)*HD + t] += EA[(g*EM + e)*HD + t] * cur[(g*KN + s)*HD + t];
    }
    __syncthreads();

    // r = relu(z @ W1 + b1) -> cur
    float acc[KN];
    #pragma unroll
    for (int k = 0; k < KN; ++k) acc[k] = b1;
    for (int c4 = 0; c4 < HD/4; ++c4) {
      const int c = 4*c4;
      const float w0 = W1[(c+0)*HD + t], w1 = W1[(c+1)*HD + t];
      const float w2 = W1[(c+2)*HD + t], w3 = W1[(c+3)*HD + t];
      #pragma unroll
      for (int k = 0; k < KN; ++k) {
        const float4 zv = *(const float4*)&tmp[(g*KN + k)*HD + c];
        acc[k] += zv.x*w0 + zv.y*w1 + zv.z*w2 + zv.w*w3;
      }
    }
    #pragma unroll
    for (int k = 0; k < KN; ++k) cur[(g*KN + k)*HD + t] = fmaxf(acc[k], 0.0f);
    __syncthreads();

    // h = r @ W2 + b2 -> tmp
    #pragma unroll
    for (int k = 0; k < KN; ++k) acc[k] = b2;
    for (int c4 = 0; c4 < HD/4; ++c4) {
      const int c = 4*c4;
      const float w0 = W2[(c+0)*HD + t], w1 = W2[(c+1)*HD + t];
      const float w2 = W2[(c+2)*HD + t], w3 = W2[(c+3)*HD + t];
      #pragma unroll
      for (int k = 0; k < KN; ++k) {
        const float4 rv = *(const float4*)&cur[(g*KN + k)*HD + c];
        acc[k] += rv.x*w0 + rv.y*w1 + rv.z*w2 + rv.w*w3;
      }
    }
    #pragma unroll
    for (int k = 0; k < KN; ++k) tmp[(g*KN + k)*HD + t] = acc[k];
    __syncthreads();

    float* sw = cur; cur = tmp; tmp = sw;   // h now in cur
  }

  // ---- edge_agg -> tmp
  #pragma unroll
  for (int k = 0; k < KN; ++k) tmp[(g*KN + k)*HD + t] = 0.0f;
  #pragma unroll
  for (int e = 0; e < EM; ++e) {
    const int s = sidx[g][e], d = didx[g][e];
    const float v = EA[(g*EM + e)*HD + t];
    tmp[(g*KN + s)*HD + t] += v;
    tmp[(g*KN + d)*HD + t] += v;
  }
  __syncthreads();

  // ---- attention alphas (16 groups of 16 lanes; group -> (motif, node))
  {
    const int gi = tid >> 4;       // 0..15
    const int j  = tid & 15;
    const int am = gi >> 3, ak = gi & 7;
    float p = 0.0f;
    #pragma unroll
    for (int i = 0; i < 8; ++i) {
      const int c = j + 16*i;
      p += cur[(am*KN + ak)*HD + c] * attn_W[c];
    }
    #pragma unroll
    for (int i = 0; i < 8; ++i) {
      const int c = j + 16*i;
      p += tmp[(am*KN + ak)*HD + c] * attn_W[HD + c];
    }
    #pragma unroll
    for (int off = 8; off >= 1; off >>= 1) p += __shfl_xor(p, off);
    if (j == 0) als[am][ak] = 1.0f / (1.0f + __expf(-(p + attn_b[0])));
  }
  __syncthreads();

  // ---- h_nodes (register) + emlp projections P1,P2 (from h), P3 (from ea)
  float hn = 0.0f;
  #pragma unroll
  for (int k = 0; k < KN; ++k) hn += als[g][k] * cur[(g*KN + k)*HD + t];

  float p1[KN], p2[KN];
  #pragma unroll
  for (int k = 0; k < KN; ++k) { p1[k] = 0.0f; p2[k] = 0.0f; }
  for (int c4 = 0; c4 < HD/4; ++c4) {
    const int c = 4*c4;
    const float wa0 = emlp_W[(c+0)*HD + t], wa1 = emlp_W[(c+1)*HD + t];
    const float wa2 = emlp_W[(c+2)*HD + t], wa3 = emlp_W[(c+3)*HD + t];
    const float wb0 = emlp_W[(HD+c+0)*HD + t], wb1 = emlp_W[(HD+c+1)*HD + t];
    const float wb2 = emlp_W[(HD+c+2)*HD + t], wb3 = emlp_W[(HD+c+3)*HD + t];
    #pragma unroll
    for (int k = 0; k < KN; ++k) {
      const float4 hv = *(const float4*)&cur[(g*KN + k)*HD + c];
      p1[k] += hv.x*wa0 + hv.y*wa1 + hv.z*wa2 + hv.w*wa3;
      p2[k] += hv.x*wb0 + hv.y*wb1 + hv.z*wb2 + hv.w*wb3;
    }
  }
  float p3[EM];
  #pragma unroll
  for (int e = 0; e < EM; ++e) p3[e] = 0.0f;
  for (int c4 = 0; c4 < HD/4; ++c4) {
    const int c = 4*c4;
    const float wc0 = emlp_W[(2*HD+c+0)*HD + t], wc1 = emlp_W[(2*HD+c+1)*HD + t];
    const float wc2 = emlp_W[(2*HD+c+2)*HD + t], wc3 = emlp_W[(2*HD+c+3)*HD + t];
    #pragma unroll
    for (int e = 0; e < EM; ++e) {
      const float4 ev = *(const float4*)&EA[(g*EM + e)*HD + c];
      p3[e] += ev.x*wc0 + ev.y*wc1 + ev.z*wc2 + ev.w*wc3;
    }
  }
  __syncthreads();
  #pragma unroll
  for (int k = 0; k < KN; ++k) { cur[(g*KN + k)*HD + t] = p1[k]; tmp[(g*KN + k)*HD + t] = p2[k]; }
  #pragma unroll
  for (int e = 0; e < EM; ++e) EA[(g*EM + e)*HD + t] = p3[e];
  __syncthreads();

  // ---- h_edges + cat
  {
    const float be = emlp_b[t];
    float he = 0.0f;
    #pragma unroll
    for (int e = 0; e < EM; ++e) {
      const int s = sidx[g][e], d = didx[g][e];
      const float v = cur[(g*KN + s)*HD + t] + tmp[(g*KN + d)*HD + t] + EA[(g*EM + e)*HD + t] + be;
      he += fmaxf(v, 0.0f);
    }
    he *= 0.1f;
    catb[g][t] = hn + he;
  }
  __syncthreads();

  // ---- motifs_X = cat @ motif_W_top + TM[type] + motif_b
  {
    float acc = motif_b[t] + ws[WS_TM + tty[g]*HD + t];
    for (int c4 = 0; c4 < HD/4; ++c4) {
      const int c = 4*c4;
      const float w0 = motif_W[(c+0)*HD + t], w1 = motif_W[(c+1)*HD + t];
      const float w2 = motif_W[(c+2)*HD + t], w3 = motif_W[(c+3)*HD + t];
      const float4 cv = *(const float4*)&catb[g][c];
      acc += cv.x*w0 + cv.y*w1 + cv.z*w2 + cv.w*w3;
    }
    out[(size_t)(m0 + g)*HD + t] = acc;
  }
}

__global__ __launch_bounds__(256) void edge_kernel(
    const float* __restrict__ x, const float* __restrict__ eag,
    const int* __restrict__ motif_types, const int* __restrict__ mei,
    const int* __restrict__ attr_nodes, const int* __restrict__ attr_edges,
    const float* __restrict__ ws, float* __restrict__ out, int ME_)
{
  __shared__ int   ani[EPB][6];
  __shared__ int   aei[EPB][8];
  __shared__ float sxl[EPB][9];
  __shared__ float sel[EPB][3];
  __shared__ int   tei[EPB];

  const int tid = threadIdx.x;
  const int t = tid & (HD - 1);
  const int g = tid >> 7;
  const int me0 = blockIdx.x * EPB;

  if (tid < EPB*6) ani[tid/6][tid%6] = attr_nodes[(size_t)(me0 + tid/6)*6 + tid%6];
  if (tid >= 32 && tid < 32 + EPB*8) { int i = tid-32; aei[i/8][i%8] = attr_edges[(size_t)(me0 + i/8)*8 + i%8]; }
  if (tid >= 64 && tid < 64 + EPB) {
    const int e = tid - 64;
    const int a0 = mei[me0 + e], b0 = mei[ME_ + me0 + e];
    tei[e] = motif_types[a0]*4 + motif_types[b0];
  }
  __syncthreads();

  if (tid < EPB*9) {
    const int e = tid/9, a = tid%9;
    float s = 0.0f;
    #pragma unroll
    for (int p = 0; p < 6; ++p) s += x[(size_t)ani[e][p]*9 + a];
    sxl[e][a] = s;
  }
  if (tid >= 32 && tid < 32 + EPB*3) {
    const int i = tid-32, e = i/3, a = i%3;
    float s = 0.0f;
    #pragma unroll
    for (int p = 0; p < 8; ++p) s += eag[(size_t)aei[e][p]*3 + a];
    sel[e][a] = s;
  }
  __syncthreads();

  float acc = ws[WS_CVEC + t] + ws[WS_TE + tei[g]*HD + t];
  #pragma unroll
  for (int a = 0; a < 9; ++a) acc += sxl[g][a] * ws[WS_AW2 + a*HD + t];
  #pragma unroll
  for (int a = 0; a < 3; ++a) acc += sel[g][a] * ws[WS_EW2 + a*HD + t];
  out[(size_t)(me0 + g)*HD + t] = acc;
}

extern "C" void kernel_launch(void* const* d_in, const int* in_sizes, int n_in,
                              void* d_out, int out_size, void* d_ws, size_t ws_size,
                              hipStream_t stream) {
  const float* x          = (const float*)d_in[0];
  const float* eag        = (const float*)d_in[1];
  const int*   motif_nodes= (const int*)d_in[2];
  const int*   motif_types= (const int*)d_in[3];
  const int*   m_src      = (const int*)d_in[4];
  const int*   m_dst      = (const int*)d_in[5];
  const int*   m_eidx     = (const int*)d_in[6];
  const int*   mei        = (const int*)d_in[7];
  const int*   attr_nodes = (const int*)d_in[8];
  const int*   attr_edges = (const int*)d_in[9];
  const float* type_emb   = (const float*)d_in[10];
  const float* atom_W     = (const float*)d_in[11];
  const float* atom_b     = (const float*)d_in[12];
  const float* edge_W     = (const float*)d_in[13];
  const float* edge_b     = (const float*)d_in[14];
  const float* conv_W1    = (const float*)d_in[15];
  const float* conv_b1    = (const float*)d_in[16];
  const float* conv_W2    = (const float*)d_in[17];
  const float* conv_b2    = (const float*)d_in[18];
  const float* conv_eps   = (const float*)d_in[19];
  const float* attn_W     = (const float*)d_in[20];
  const float* attn_b     = (const float*)d_in[21];
  const float* emlp_W     = (const float*)d_in[22];
  const float* emlp_b     = (const float*)d_in[23];
  const float* motif_W    = (const float*)d_in[24];
  const float* motif_b    = (const float*)d_in[25];
  const float* me_W       = (const float*)d_in[26];
  const float* me_b       = (const float*)d_in[27];

  const int N_  = in_sizes[0] / 9;
  const int M_  = in_sizes[2] / 8;
  const int ME_ = in_sizes[7] / 2;

  float* ws  = (float*)d_ws;
  float* out = (float*)d_out;

  precompute_kernel<<<33, 128, 0, stream>>>(type_emb, atom_W, atom_b, edge_W, edge_b,
                                            motif_W, me_W, me_b, (float)N_, ws);
  motif_kernel<<<M_/MPB, 256, 0, stream>>>(x, eag, motif_nodes, motif_types, m_src, m_dst, m_eidx,
      atom_W, atom_b, edge_W, edge_b, conv_W1, conv_b1, conv_W2, conv_b2, conv_eps,
      attn_W, attn_b, emlp_W, emlp_b, motif_W, motif_b, ws, out);
  edge_kernel<<<ME_/EPB, 256, 0, stream>>>(x, eag, motif_types, mei, attr_nodes, attr_edges,
                                           ws, out + (size_t)M_*HD, ME_);
}

// Round 2
// 1038.154 us; speedup vs baseline: 2.1558x; 2.1558x over previous
//
#include <hip/hip_runtime.h>
#include <hip/hip_bf16.h>
#include <math.h>

#define HD 128
#define MPB 8
#define EPB 2

typedef __attribute__((ext_vector_type(8))) short short8;
typedef __attribute__((ext_vector_type(4))) float f32x4;
typedef unsigned short ushort_t;
typedef unsigned int uint32;

#define MFMA(a, b, c) __builtin_amdgcn_mfma_f32_16x16x32_bf16(a, b, c, 0, 0, 0)

// ---- ws layout ----
// f32 tables at float offsets:
#define WS_TE   0        // 16*128
#define WS_TM   2048     // 4*128
#define WS_AW2  2560     // 9*128
#define WS_EW2  3712     // 3*128
#define WS_CVEC 4096     // 128
// bf16 fragment buffer at byte offset FB_OFF:
//   wi 0..7 (128x128 weights): base = wi*32768 bytes, 32 tiles of 1KB
//   wi 8 (atom_W pad K=32): base 262144, 8 tiles ; wi 9 (edge_W pad): base 270336
#define FB_OFF 32768

__device__ __forceinline__ float bf2f(ushort_t u) {
  union { float f; uint32 i; } c; c.i = ((uint32)u) << 16; return c.f;
}
__device__ __forceinline__ ushort_t f2bf(float f) {
  union { float ff; uint32 u; } c; c.ff = f;
  uint32 r = c.u + 0x7fff + ((c.u >> 16) & 1);
  return (ushort_t)(r >> 16);
}
// byte offset in a 256B-row swizzled bf16 buffer
__device__ __forceinline__ int off256(int row, int by) {
  return row * 256 + (by ^ ((row & 7) << 4));
}

// ================= precompute: f32 tables =================
__global__ __launch_bounds__(128) void precompute_kernel(
    const float* __restrict__ type_emb, const float* __restrict__ atom_W,
    const float* __restrict__ atom_b, const float* __restrict__ edge_W,
    const float* __restrict__ edge_b, const float* __restrict__ motif_W,
    const float* __restrict__ me_W, const float* __restrict__ me_b,
    float n_nodes, float* __restrict__ ws)
{
  const int t = threadIdx.x;
  const int r = blockIdx.x;
  float acc = 0.0f;
  if (r < 16) {
    const int sc = r >> 2, ec = r & 3;
    for (int c = 0; c < HD; ++c)
      acc += (type_emb[sc*HD + c] + type_emb[ec*HD + c]) * me_W[c*HD + t];
    ws[WS_TE + r*HD + t] = acc;
  } else if (r < 20) {
    const int ty = r - 16;
    for (int c = 0; c < HD; ++c) {
      float tv = type_emb[ty*HD + c] * (c >= 64 ? n_nodes : 1.0f);
      acc += tv * motif_W[(HD + c)*HD + t];
    }
    ws[WS_TM + ty*HD + t] = acc;
  } else if (r < 29) {
    const int a = r - 20;
    for (int c = 0; c < HD; ++c)
      acc += atom_W[a*HD + c] * me_W[(HD + c)*HD + t];
    ws[WS_AW2 + a*HD + t] = acc;
  } else if (r < 32) {
    const int a = r - 29;
    for (int c = 0; c < HD; ++c)
      acc += edge_W[a*HD + c] * me_W[(HD + c)*HD + t];
    ws[WS_EW2 + a*HD + t] = acc;
  } else {
    acc = me_b[t];
    for (int c = 0; c < HD; ++c)
      acc += (6.0f*atom_b[c] + 8.0f*edge_b[c]) * me_W[(HD + c)*HD + t];
    ws[WS_CVEC + t] = acc;
  }
}

// ================= precompute: bf16 MFMA fragment buffer =================
// B-fragment layout for mfma_f32_16x16x32_bf16: lane l holds B[kt*32+8*(l>>4)+j][nt*16+(l&15)]
__global__ __launch_bounds__(64) void frag_kernel(
    const float* __restrict__ conv_W1, const float* __restrict__ conv_W2,
    const float* __restrict__ emlp_W, const float* __restrict__ motif_W,
    const float* __restrict__ atom_W, const float* __restrict__ edge_W,
    ushort_t* __restrict__ fbo)
{
  const int bid = blockIdx.x, l = threadIdx.x;
  int wi, kt, nt;
  if (bid < 256) { wi = bid >> 5; kt = (bid >> 3) & 3; nt = bid & 7; }
  else { int r = bid - 256; wi = 8 + (r >> 3); kt = 0; nt = r & 7; }
  const float* src; int Klim = 128;
  switch (wi) {
    case 0: src = conv_W1; break;
    case 1: src = conv_W2; break;
    case 2: src = conv_W1 + 16384; break;
    case 3: src = conv_W2 + 16384; break;
    case 4: src = emlp_W; break;
    case 5: src = emlp_W + 16384; break;
    case 6: src = emlp_W + 32768; break;
    case 7: src = motif_W; break;
    case 8: src = atom_W; Klim = 9; break;
    default: src = edge_W; Klim = 3; break;
  }
  size_t base = (wi < 8) ? (size_t)wi * 16384 : (size_t)131072 + (size_t)(wi - 8) * 4096;
  ushort_t* dst = fbo + base + ((size_t)(kt * 8 + nt) * 64 + l) * 8;
  #pragma unroll
  for (int j = 0; j < 8; ++j) {
    int k = kt * 32 + ((l >> 4) << 3) + j;
    int n = nt * 16 + (l & 15);
    float f = (k < Klim) ? src[k * HD + n] : 0.0f;
    dst[j] = f2bf(f);
  }
}

// ================= motif kernel =================
__global__ __launch_bounds__(256, 2) void motif_kernel(
    const float* __restrict__ x, const float* __restrict__ eag,
    const int* __restrict__ motif_nodes, const int* __restrict__ motif_types,
    const int* __restrict__ m_src, const int* __restrict__ m_dst,
    const int* __restrict__ m_eidx,
    const float* __restrict__ atom_b, const float* __restrict__ edge_b,
    const float* __restrict__ conv_b1, const float* __restrict__ conv_b2,
    const float* __restrict__ conv_eps,
    const float* __restrict__ attn_W, const float* __restrict__ attn_b,
    const float* __restrict__ emlp_b, const float* __restrict__ motif_b,
    const float* __restrict__ wsf, const ushort_t* __restrict__ fb,
    float* __restrict__ out)
{
  __shared__ __align__(16) char Hb[64 * 256];    // h / r / h_new / P1 (bf16, swizzled)
  __shared__ __align__(16) char Tb[64 * 256];    // xp+ep at init; z; P2
  __shared__ __align__(16) char EAb[80 * 256];   // ea / P3
  __shared__ __align__(16) char Cb[16 * 256];    // cat (rows 8..15 zero)
  __shared__ int nidx[64], sidx[80], didx[80], geidx[80], tty[8];
  __shared__ float qv[80], qsum[64], alph[64];

  const int tid  = threadIdx.x;
  const int lane = tid & 63;
  const int wid  = tid >> 6;
  const int cl   = lane & 15;     // MFMA col / A-row-within-tile
  const int rg   = lane >> 4;     // MFMA k-group / D-row-group
  const int ch   = tid & 127;     // elementwise channel
  const int half = tid >> 7;
  const int m0   = blockIdx.x * MPB;

  // ---------- init ----------
  if (tid < 64) { nidx[tid] = motif_nodes[(size_t)m0 * 8 + tid]; qsum[tid] = 0.0f; }
  if (tid < 80) {
    sidx[tid]  = m_src [(size_t)m0 * 10 + tid];
    didx[tid]  = m_dst [(size_t)m0 * 10 + tid];
    geidx[tid] = m_eidx[(size_t)m0 * 10 + tid];
  }
  if (tid < 8) tty[tid] = motif_types[m0 + tid];
  { uint4 z4 = make_uint4(0, 0, 0, 0); *(uint4*)(Cb + tid * 16) = z4; }
  __syncthreads();

  // pad-stage xp [64][32] (rows 64B, row&3 swizzle) and ep [80][32] into Tb
  for (int i = tid; i < 64 * 32; i += 256) {
    int row = i >> 5, k = i & 31;
    float f = (k < 9) ? x[(size_t)nidx[row] * 9 + k] : 0.0f;
    *(ushort_t*)(Tb + row * 64 + ((k * 2) ^ ((row & 3) << 4))) = f2bf(f);
  }
  for (int i = tid; i < 80 * 32; i += 256) {
    int row = i >> 5, k = i & 31;
    float f = (k < 3) ? eag[(size_t)geidx[row] * 3 + k] : 0.0f;
    *(ushort_t*)(Tb + 4096 + row * 64 + ((k * 2) ^ ((row & 3) << 4))) = f2bf(f);
  }
  __syncthreads();

  // ---------- h0 = xp @ atomW + atom_b ; ea = ep @ edgeW + edge_b ----------
  {
    const ushort_t* fbA = fb + 131072;           // wi8
    {
      int rb = wid * 16;
      int row = rb + cl;
      short8 a = *(const short8*)(Tb + row * 64 + ((rg << 4) ^ ((row & 3) << 4)));
      f32x4 acc[8];
      #pragma unroll
      for (int nt = 0; nt < 8; ++nt) { float bv = atom_b[nt * 16 + cl]; acc[nt] = f32x4{bv, bv, bv, bv}; }
      #pragma unroll
      for (int nt = 0; nt < 8; ++nt) {
        short8 b = *(const short8*)(fbA + ((size_t)nt * 64 + lane) * 8);
        acc[nt] = MFMA(a, b, acc[nt]);
      }
      #pragma unroll
      for (int nt = 0; nt < 8; ++nt)
        #pragma unroll
        for (int i = 0; i < 4; ++i) {
          int row2 = rb + rg * 4 + i;
          *(ushort_t*)(Hb + off256(row2, (nt * 16 + cl) * 2)) = f2bf(acc[nt][i]);
        }
    }
    const ushort_t* fbE = fb + 131072 + 4096;    // wi9
    for (int mt = wid; mt < 5; mt += 4) {
      int rb = mt * 16;
      int row = rb + cl;
      short8 a = *(const short8*)(Tb + 4096 + row * 64 + ((rg << 4) ^ ((row & 3) << 4)));
      f32x4 acc[8];
      #pragma unroll
      for (int nt = 0; nt < 8; ++nt) { float bv = edge_b[nt * 16 + cl]; acc[nt] = f32x4{bv, bv, bv, bv}; }
      #pragma unroll
      for (int nt = 0; nt < 8; ++nt) {
        short8 b = *(const short8*)(fbE + ((size_t)nt * 64 + lane) * 8);
        acc[nt] = MFMA(a, b, acc[nt]);
      }
      #pragma unroll
      for (int nt = 0; nt < 8; ++nt)
        #pragma unroll
        for (int i = 0; i < 4; ++i) {
          int row2 = rb + rg * 4 + i;
          *(ushort_t*)(EAb + off256(row2, (nt * 16 + cl) * 2)) = f2bf(acc[nt][i]);
        }
    }
  }
  __syncthreads();

  // ---------- conv layers ----------
  for (int l = 0; l < 2; ++l) {
    const float epl = 1.0f + conv_eps[l];
    // z-phase: z = (1+eps)*h + scatter_dst(ea * h_src)   (bf16 RMW in Tb)
    #pragma unroll
    for (int mi = 0; mi < 4; ++mi) {
      int m = half * 4 + mi, r0 = m * 8;
      #pragma unroll
      for (int k = 0; k < 8; ++k) {
        float hv = bf2f(*(const ushort_t*)(Hb + off256(r0 + k, ch * 2)));
        *(ushort_t*)(Tb + off256(r0 + k, ch * 2)) = f2bf(epl * hv);
      }
      #pragma unroll
      for (int e = 0; e < 10; ++e) {
        int s = sidx[m * 10 + e], d = didx[m * 10 + e];
        float eav = bf2f(*(const ushort_t*)(EAb + off256(m * 10 + e, ch * 2)));
        float hs  = bf2f(*(const ushort_t*)(Hb  + off256(r0 + s, ch * 2)));
        float zc  = bf2f(*(const ushort_t*)(Tb  + off256(r0 + d, ch * 2)));
        *(ushort_t*)(Tb + off256(r0 + d, ch * 2)) = f2bf(zc + eav * hs);
      }
    }
    __syncthreads();

    // GEMM1: r = relu(z @ W1 + b1) -> Hb
    {
      const ushort_t* fbW = fb + (size_t)(2 * l) * 16384;
      int rb = wid * 16;
      f32x4 acc[8];
      #pragma unroll
      for (int nt = 0; nt < 8; ++nt) { float bv = conv_b1[l * HD + nt * 16 + cl]; acc[nt] = f32x4{bv, bv, bv, bv}; }
      #pragma unroll
      for (int kt = 0; kt < 4; ++kt) {
        int row = rb + cl;
        short8 a = *(const short8*)(Tb + off256(row, kt * 64 + (rg << 4)));
        short8 bfr[8];
        #pragma unroll
        for (int nt = 0; nt < 8; ++nt) bfr[nt] = *(const short8*)(fbW + ((size_t)(kt * 8 + nt) * 64 + lane) * 8);
        #pragma unroll
        for (int nt = 0; nt < 8; ++nt) acc[nt] = MFMA(a, bfr[nt], acc[nt]);
      }
      #pragma unroll
      for (int nt = 0; nt < 8; ++nt)
        #pragma unroll
        for (int i = 0; i < 4; ++i) {
          int row2 = rb + rg * 4 + i;
          *(ushort_t*)(Hb + off256(row2, (nt * 16 + cl) * 2)) = f2bf(fmaxf(acc[nt][i], 0.0f));
        }
    }
    // GEMM2: h = r @ W2 + b2 -> Hb (wave-local rows; no barrier needed)
    {
      const ushort_t* fbW = fb + (size_t)(2 * l + 1) * 16384;
      int rb = wid * 16;
      f32x4 acc[8];
      #pragma unroll
      for (int nt = 0; nt < 8; ++nt) { float bv = conv_b2[l * HD + nt * 16 + cl]; acc[nt] = f32x4{bv, bv, bv, bv}; }
      #pragma unroll
      for (int kt = 0; kt < 4; ++kt) {
        int row = rb + cl;
        short8 a = *(const short8*)(Hb + off256(row, kt * 64 + (rg << 4)));
        short8 bfr[8];
        #pragma unroll
        for (int nt = 0; nt < 8; ++nt) bfr[nt] = *(const short8*)(fbW + ((size_t)(kt * 8 + nt) * 64 + lane) * 8);
        #pragma unroll
        for (int nt = 0; nt < 8; ++nt) acc[nt] = MFMA(a, bfr[nt], acc[nt]);
      }
      #pragma unroll
      for (int nt = 0; nt < 8; ++nt)
        #pragma unroll
        for (int i = 0; i < 4; ++i) {
          int row2 = rb + rg * 4 + i;
          *(ushort_t*)(Hb + off256(row2, (nt * 16 + cl) * 2)) = f2bf(acc[nt][i]);
        }
    }
    __syncthreads();
  }

  // ---------- attention ----------
  {
    int j = tid & 3;
    for (int r = tid >> 2; r < 80; r += 64) {
      float p = 0.0f;
      #pragma unroll
      for (int i = 0; i < 32; ++i) {
        int c = i * 4 + j;
        p += bf2f(*(const ushort_t*)(EAb + off256(r, c * 2))) * attn_W[HD + c];
      }
      p += __shfl_xor(p, 1); p += __shfl_xor(p, 2);
      if (j == 0) qv[r] = p;
    }
  }
  __syncthreads();
  if (tid < 8) {
    int m = tid;
    #pragma unroll
    for (int e = 0; e < 10; ++e) {
      float q = qv[m * 10 + e];
      qsum[m * 8 + sidx[m * 10 + e]] += q;
      qsum[m * 8 + didx[m * 10 + e]] += q;
    }
  }
  __syncthreads();
  {
    int j = tid & 3, r = tid >> 2;
    float p = 0.0f;
    #pragma unroll
    for (int i = 0; i < 32; ++i) {
      int c = i * 4 + j;
      p += bf2f(*(const ushort_t*)(Hb + off256(r, c * 2))) * attn_W[c];
    }
    p += __shfl_xor(p, 1); p += __shfl_xor(p, 2);
    if (j == 0) alph[r] = 1.0f / (1.0f + __expf(-(p + qsum[r] + attn_b[0])));
  }
  __syncthreads();

  // h_nodes in regs
  float hn[4];
  #pragma unroll
  for (int mi = 0; mi < 4; ++mi) {
    int m = half * 4 + mi, r0 = m * 8;
    float s = 0.0f;
    #pragma unroll
    for (int k = 0; k < 8; ++k)
      s += alph[r0 + k] * bf2f(*(const ushort_t*)(Hb + off256(r0 + k, ch * 2)));
    hn[mi] = s;
  }
  __syncthreads();   // all reads of Hb done before P1 overwrites

  // ---------- emlp: P1 -> Hb, P2 -> Tb, P3 -> EAb (in place) ----------
  {
    const ushort_t* fbA = fb + (size_t)4 * 16384;
    const ushort_t* fbB = fb + (size_t)5 * 16384;
    int rb = wid * 16;
    f32x4 pa[8], pb[8];
    #pragma unroll
    for (int nt = 0; nt < 8; ++nt) { pa[nt] = f32x4{0, 0, 0, 0}; pb[nt] = f32x4{0, 0, 0, 0}; }
    #pragma unroll
    for (int kt = 0; kt < 4; ++kt) {
      int row = rb + cl;
      short8 a = *(const short8*)(Hb + off256(row, kt * 64 + (rg << 4)));
      #pragma unroll
      for (int nt = 0; nt < 8; ++nt) {
        short8 ba = *(const short8*)(fbA + ((size_t)(kt * 8 + nt) * 64 + lane) * 8);
        short8 bb = *(const short8*)(fbB + ((size_t)(kt * 8 + nt) * 64 + lane) * 8);
        pa[nt] = MFMA(a, ba, pa[nt]);
        pb[nt] = MFMA(a, bb, pb[nt]);
      }
    }
    #pragma unroll
    for (int nt = 0; nt < 8; ++nt)
      #pragma unroll
      for (int i = 0; i < 4; ++i) {
        int row2 = rb + rg * 4 + i;
        *(ushort_t*)(Hb + off256(row2, (nt * 16 + cl) * 2)) = f2bf(pa[nt][i]);
        *(ushort_t*)(Tb + off256(row2, (nt * 16 + cl) * 2)) = f2bf(pb[nt][i]);
      }
    const ushort_t* fbC = fb + (size_t)6 * 16384;
    for (int mt = wid; mt < 5; mt += 4) {
      int rb2 = mt * 16;
      f32x4 pc[8];
      #pragma unroll
      for (int nt = 0; nt < 8; ++nt) pc[nt] = f32x4{0, 0, 0, 0};
      #pragma unroll
      for (int kt = 0; kt < 4; ++kt) {
        int row = rb2 + cl;
        short8 a = *(const short8*)(EAb + off256(row, kt * 64 + (rg << 4)));
        #pragma unroll
        for (int nt = 0; nt < 8; ++nt) {
          short8 b = *(const short8*)(fbC + ((size_t)(kt * 8 + nt) * 64 + lane) * 8);
          pc[nt] = MFMA(a, b, pc[nt]);
        }
      }
      #pragma unroll
      for (int nt = 0; nt < 8; ++nt)
        #pragma unroll
        for (int i = 0; i < 4; ++i) {
          int row2 = rb2 + rg * 4 + i;
          *(ushort_t*)(EAb + off256(row2, (nt * 16 + cl) * 2)) = f2bf(pc[nt][i]);
        }
    }
  }
  __syncthreads();

  // ---------- h_edges + cat ----------
  {
    float eb = emlp_b[ch];
    #pragma unroll
    for (int mi = 0; mi < 4; ++mi) {
      int m = half * 4 + mi, r0 = m * 8;
      float he = 0.0f;
      #pragma unroll
      for (int e = 0; e < 10; ++e) {
        int s = sidx[m * 10 + e], d = didx[m * 10 + e];
        float v = bf2f(*(const ushort_t*)(Hb  + off256(r0 + s, ch * 2)))
                + bf2f(*(const ushort_t*)(Tb  + off256(r0 + d, ch * 2)))
                + bf2f(*(const ushort_t*)(EAb + off256(m * 10 + e, ch * 2))) + eb;
        he += fmaxf(v, 0.0f);
      }
      float cat = hn[mi] + 0.1f * he;
      *(ushort_t*)(Cb + off256(m, ch * 2)) = f2bf(cat);
    }
  }
  __syncthreads();

  // ---------- final: out = cat @ motifW_top + TM[type] + motif_b ----------
  {
    const ushort_t* fbM = fb + (size_t)7 * 16384;
    f32x4 acc[2];
    acc[0] = f32x4{0, 0, 0, 0}; acc[1] = f32x4{0, 0, 0, 0};
    #pragma unroll
    for (int kt = 0; kt < 4; ++kt) {
      int row = cl;
      short8 a = *(const short8*)(Cb + off256(row, kt * 64 + (rg << 4)));
      #pragma unroll
      for (int j = 0; j < 2; ++j) {
        int nt = wid * 2 + j;
        short8 b = *(const short8*)(fbM + ((size_t)(kt * 8 + nt) * 64 + lane) * 8);
        acc[j] = MFMA(a, b, acc[j]);
      }
    }
    #pragma unroll
    for (int j = 0; j < 2; ++j)
      #pragma unroll
      for (int i = 0; i < 4; ++i) {
        int row = rg * 4 + i;
        if (row < 8) {
          int nt = wid * 2 + j, col = nt * 16 + cl;
          out[(size_t)(m0 + row) * HD + col] = acc[j][i] + motif_b[col] + wsf[WS_TM + tty[row] * HD + col];
        }
      }
  }
}

// ================= edge kernel (unchanged from round 1) =================
__global__ __launch_bounds__(256) void edge_kernel(
    const float* __restrict__ x, const float* __restrict__ eag,
    const int* __restrict__ motif_types, const int* __restrict__ mei,
    const int* __restrict__ attr_nodes, const int* __restrict__ attr_edges,
    const float* __restrict__ ws, float* __restrict__ out, int ME_)
{
  __shared__ int   ani[EPB][6];
  __shared__ int   aei[EPB][8];
  __shared__ float sxl[EPB][9];
  __shared__ float sel[EPB][3];
  __shared__ int   tei[EPB];

  const int tid = threadIdx.x;
  const int t = tid & (HD - 1);
  const int g = tid >> 7;
  const int me0 = blockIdx.x * EPB;

  if (tid < EPB*6) ani[tid/6][tid%6] = attr_nodes[(size_t)(me0 + tid/6)*6 + tid%6];
  if (tid >= 32 && tid < 32 + EPB*8) { int i = tid-32; aei[i/8][i%8] = attr_edges[(size_t)(me0 + i/8)*8 + i%8]; }
  if (tid >= 64 && tid < 64 + EPB) {
    const int e = tid - 64;
    const int a0 = mei[me0 + e], b0 = mei[ME_ + me0 + e];
    tei[e] = motif_types[a0]*4 + motif_types[b0];
  }
  __syncthreads();

  if (tid < EPB*9) {
    const int e = tid/9, a = tid%9;
    float s = 0.0f;
    #pragma unroll
    for (int p = 0; p < 6; ++p) s += x[(size_t)ani[e][p]*9 + a];
    sxl[e][a] = s;
  }
  if (tid >= 32 && tid < 32 + EPB*3) {
    const int i = tid-32, e = i/3, a = i%3;
    float s = 0.0f;
    #pragma unroll
    for (int p = 0; p < 8; ++p) s += eag[(size_t)aei[e][p]*3 + a];
    sel[e][a] = s;
  }
  __syncthreads();

  float acc = ws[WS_CVEC + t] + ws[WS_TE + tei[g]*HD + t];
  #pragma unroll
  for (int a = 0; a < 9; ++a) acc += sxl[g][a] * ws[WS_AW2 + a*HD + t];
  #pragma unroll
  for (int a = 0; a < 3; ++a) acc += sel[g][a] * ws[WS_EW2 + a*HD + t];
  out[(size_t)(me0 + g)*HD + t] = acc;
}

extern "C" void kernel_launch(void* const* d_in, const int* in_sizes, int n_in,
                              void* d_out, int out_size, void* d_ws, size_t ws_size,
                              hipStream_t stream) {
  const float* x          = (const float*)d_in[0];
  const float* eag        = (const float*)d_in[1];
  const int*   motif_nodes= (const int*)d_in[2];
  const int*   motif_types= (const int*)d_in[3];
  const int*   m_src      = (const int*)d_in[4];
  const int*   m_dst      = (const int*)d_in[5];
  const int*   m_eidx     = (const int*)d_in[6];
  const int*   mei        = (const int*)d_in[7];
  const int*   attr_nodes = (const int*)d_in[8];
  const int*   attr_edges = (const int*)d_in[9];
  const float* type_emb   = (const float*)d_in[10];
  const float* atom_W     = (const float*)d_in[11];
  const float* atom_b     = (const float*)d_in[12];
  const float* edge_W     = (const float*)d_in[13];
  const float* edge_b     = (const float*)d_in[14];
  const float* conv_W1    = (const float*)d_in[15];
  const float* conv_b1    = (const float*)d_in[16];
  const float* conv_W2    = (const float*)d_in[17];
  const float* conv_b2    = (const float*)d_in[18];
  const float* conv_eps   = (const float*)d_in[19];
  const float* attn_W     = (const float*)d_in[20];
  const float* attn_b     = (const float*)d_in[21];
  const float* emlp_W     = (const float*)d_in[22];
  const float* emlp_b     = (const float*)d_in[23];
  const float* motif_W    = (const float*)d_in[24];
  const float* motif_b    = (const float*)d_in[25];
  const float* me_W       = (const float*)d_in[26];
  const float* me_b       = (const float*)d_in[27];

  const int N_  = in_sizes[0] / 9;
  const int M_  = in_sizes[2] / 8;
  const int ME_ = in_sizes[7] / 2;

  float* wsf = (float*)d_ws;
  ushort_t* fb = (ushort_t*)((char*)d_ws + FB_OFF);
  float* out = (float*)d_out;

  precompute_kernel<<<33, 128, 0, stream>>>(type_emb, atom_W, atom_b, edge_W, edge_b,
                                            motif_W, me_W, me_b, (float)N_, wsf);
  frag_kernel<<<272, 64, 0, stream>>>(conv_W1, conv_W2, emlp_W, motif_W, atom_W, edge_W, fb);
  motif_kernel<<<M_/MPB, 256, 0, stream>>>(x, eag, motif_nodes, motif_types, m_src, m_dst, m_eidx,
      atom_b, edge_b, conv_b1, conv_b2, conv_eps, attn_W, attn_b, emlp_b, motif_b,
      wsf, fb, out);
  edge_kernel<<<ME_/EPB, 256, 0, stream>>>(x, eag, motif_types, mei, attr_nodes, attr_edges,
                                           wsf, out + (size_t)M_*HD, ME_);
}